// Round 1
// baseline (1563.394 us; speedup 1.0000x reference)
//
#include <hip/hip_runtime.h>

typedef unsigned short u16;
typedef __attribute__((ext_vector_type(4))) unsigned short u16x4;
typedef __attribute__((ext_vector_type(8))) short short8;
typedef __attribute__((ext_vector_type(4))) float f32x4;

#define DEV static __device__ __forceinline__

constexpr int NB   = 16;
constexpr int S    = 512;
constexpr int DM   = 4096;
constexpr int NH   = 32;
constexpr int NKV  = 8;
constexpr int HD   = 128;
constexpr int TOK  = NB * S;          // 8192
constexpr int NQKV = 6144;            // 4096 q + 1024 k + 1024 v
constexpr float ATT_SCALE = 0.08838834764831845f;  // 1/sqrt(128)

DEV u16 f2b(float f) {
  union { float f; unsigned u; } v; v.f = f;
  unsigned r = v.u + 0x7fffu + ((v.u >> 16) & 1u);
  return (u16)(r >> 16);
}
DEV float b2f(u16 u) {
  union { unsigned u; float f; } v; v.u = ((unsigned)u) << 16;
  return v.f;
}
DEV void async16(const void* g, void* l) {
  __builtin_amdgcn_global_load_lds(
      (const __attribute__((address_space(1))) unsigned int*)g,
      (__attribute__((address_space(3))) unsigned int*)l, 16, 0, 0);
}

// ---------------- f32 -> bf16 convert (hidden states) ----------------
__global__ void k_cvt_bf16(const float* __restrict__ src, u16* __restrict__ dst) {
  int i = (blockIdx.x * 256 + threadIdx.x) * 4;
  const float4 v = *reinterpret_cast<const float4*>(src + i);
  u16x4 o;
  o[0] = f2b(v.x); o[1] = f2b(v.y); o[2] = f2b(v.z); o[3] = f2b(v.w);
  *reinterpret_cast<u16x4*>(dst + i) = o;
}

// ---------------- weight transpose: src[K=4096][ncols] f32 -> dst[ncols][4096] bf16 ----
__global__ void k_tr_w(const float* __restrict__ src, u16* __restrict__ dst, int ncols) {
  __shared__ float tile[32][33];
  int tx = threadIdx.x, ty = threadIdx.y;
  int n0 = blockIdx.x * 32, k0 = blockIdx.y * 32;
#pragma unroll
  for (int i = 0; i < 32; i += 8)
    tile[ty + i][tx] = src[(size_t)(k0 + ty + i) * ncols + n0 + tx];
  __syncthreads();
#pragma unroll
  for (int i = 0; i < 32; i += 8)
    dst[(size_t)(n0 + ty + i) * 4096 + k0 + tx] = f2b(tile[tx][ty + i]);
}

// ---------------- RoPE cos/sin table per (b,s): tab[t][j] = {cos,sin}(pos*invfreq_j) ----
__global__ void k_rope_tab(const int* __restrict__ pos_ids, float2* __restrict__ tab) {
  int t = blockIdx.x;      // 0..8191
  int j = threadIdx.x;     // 0..63
  float pos = (float)pos_ids[t];
  // inv_freq_j = theta^(-2j/128) = exp(-j * ln(1e6)/64)
  float inv = expf(-(float)j * 0.21586735246819178f);
  float ang = pos * inv;
  float sv, cv;
  sincosf(ang, &sv, &cv);
  tab[t * 64 + j] = make_float2(cv, sv);
}

// ---------------- fused RMSNorm + RoPE, in-place on qkv (q and k heads) ----------------
__global__ void k_norm_rope(u16* __restrict__ qkv, const float2* __restrict__ tab,
                            const float* __restrict__ qw, const float* __restrict__ kw) {
  int wid  = blockIdx.x * 4 + (threadIdx.x >> 6);
  int lane = threadIdx.x & 63;
  int t  = wid / 40;
  int hh = wid - t * 40;
  bool isq = hh < 32;
  u16* base = qkv + (size_t)t * NQKV + (isq ? hh * 128 : 4096 + (hh - 32) * 128);
  float x1 = b2f(base[lane]);
  float x2 = b2f(base[lane + 64]);
  float ss = x1 * x1 + x2 * x2;
#pragma unroll
  for (int m = 1; m < 64; m <<= 1) ss += __shfl_xor(ss, m, 64);
  float r = rsqrtf(ss * (1.0f / 128.0f) + 1e-6f);
  const float* w = isq ? qw : kw;
  float y1 = x1 * r * w[lane];
  float y2 = x2 * r * w[lane + 64];
  float2 cs = tab[t * 64 + lane];
  float o1 = y1 * cs.x - y2 * cs.y;
  float o2 = y2 * cs.x + y1 * cs.y;
  if (isq) { o1 *= ATT_SCALE; o2 *= ATT_SCALE; }
  base[lane]      = f2b(o1);
  base[lane + 64] = f2b(o2);
}

// ---------------- V transpose: qkv v-cols [b][s][kvh][d] -> vt[b][kvh][d][s] (bf16) ----
__global__ void k_tr_v(const u16* __restrict__ qkv, u16* __restrict__ vt) {
  __shared__ u16 tile[32][33];
  int bh = blockIdx.z;           // b*8+kvh
  int b = bh >> 3, kvh = bh & 7;
  int d0 = blockIdx.x * 32, s0 = blockIdx.y * 32;
  int tx = threadIdx.x, ty = threadIdx.y;
#pragma unroll
  for (int i = 0; i < 32; i += 8)
    tile[ty + i][tx] = qkv[(size_t)(b * S + s0 + ty + i) * NQKV + 5120 + kvh * 128 + d0 + tx];
  __syncthreads();
#pragma unroll
  for (int i = 0; i < 32; i += 8)
    vt[((size_t)(bh * 128 + d0 + ty + i)) * S + s0 + tx] = tile[tx][ty + i];
}

// ---------------- GEMM: C[M][N] = A[M][K] * B[N][K]^T  (bf16 in, f32 acc) -------------
// m97 structure: 128x128 tile, BK=32, 4 waves (2x2), global_load_lds width 16.
template <int OUT_BF16>
__global__ __launch_bounds__(256) void k_gemm_bt(const u16* __restrict__ A,
                                                 const u16* __restrict__ Bm,
                                                 void* __restrict__ Cv,
                                                 int M, int N, int K) {
  __shared__ u16 Alds[128 * 32];
  __shared__ u16 Blds[128 * 32];
  const int tid = threadIdx.x;
  const int lane = tid & 63;
  const int wave = tid >> 6;
  const int nbx = N >> 7;
  const int nwg = (M >> 7) * nbx;
  // bijective XCD swizzle (nwg % 8 == 0 for our shapes)
  const int cpx = nwg >> 3;
  const int wg  = blockIdx.x;
  const int swz = (wg & 7) * cpx + (wg >> 3);
  const int bx = swz % nbx, by = swz / nbx;
  const int m0 = by << 7, n0 = bx << 7;
  const int wm = (wave >> 1) * 64, wn = (wave & 1) * 64;
  const int r16 = lane & 15, h4 = lane >> 4;

  f32x4 acc[4][4] = {};

  for (int k0 = 0; k0 < K; k0 += 32) {
    __syncthreads();
#pragma unroll
    for (int it = 0; it < 2; ++it) {
      int c = tid + 256 * it;          // chunk of 16B; row=c>>2, col8=c&3
      int row = c >> 2, col = (c & 3) * 8;
      async16(A  + (size_t)(m0 + row) * K + k0 + col, &Alds[c * 8]);
      async16(Bm + (size_t)(n0 + row) * K + k0 + col, &Blds[c * 8]);
    }
    __syncthreads();
    short8 af[4], bf[4];
#pragma unroll
    for (int i = 0; i < 4; ++i) {
      af[i] = *reinterpret_cast<const short8*>(&Alds[(wm + i * 16 + r16) * 32 + h4 * 8]);
      bf[i] = *reinterpret_cast<const short8*>(&Blds[(wn + i * 16 + r16) * 32 + h4 * 8]);
    }
#pragma unroll
    for (int i = 0; i < 4; ++i)
#pragma unroll
      for (int j = 0; j < 4; ++j)
        acc[i][j] = __builtin_amdgcn_mfma_f32_16x16x32_bf16(af[i], bf[j], acc[i][j], 0, 0, 0);
  }

  // epilogue: C/D layout col=lane&15, row=(lane>>4)*4+reg
  if (OUT_BF16) {
    u16* C = (u16*)Cv;
#pragma unroll
    for (int i = 0; i < 4; ++i)
#pragma unroll
      for (int j = 0; j < 4; ++j)
#pragma unroll
        for (int r = 0; r < 4; ++r) {
          size_t row = m0 + wm + i * 16 + h4 * 4 + r;
          size_t col = n0 + wn + j * 16 + r16;
          C[row * N + col] = f2b(acc[i][j][r]);
        }
  } else {
    float* C = (float*)Cv;
#pragma unroll
    for (int i = 0; i < 4; ++i)
#pragma unroll
      for (int j = 0; j < 4; ++j)
#pragma unroll
        for (int r = 0; r < 4; ++r) {
          size_t row = m0 + wm + i * 16 + h4 * 4 + r;
          size_t col = n0 + wn + j * 16 + r16;
          C[row * N + col] = acc[i][j][r];
        }
  }
}

// ---------------- flash attention (causal, GQA) ----------------------------------------
// grid (qblock=8, h=32, b=16), 256 threads (4 waves x 16 q-rows). QBLK=KBLK=64.
__global__ __launch_bounds__(256) void k_attn(const u16* __restrict__ qkv,
                                              const u16* __restrict__ vt,
                                              u16* __restrict__ out) {
  __shared__ u16 Klds[64 * 128];     // [key][d], XOR-swizzled
  __shared__ u16 Vlds[128 * 64];     // [d][key], XOR-swizzled
  __shared__ u16 Plds[4][16 * 64];   // per-wave P, XOR-swizzled
  const int qb = blockIdx.x, h = blockIdx.y, b = blockIdx.z;
  const int kvh = h >> 2;
  const int tid = threadIdx.x, lane = tid & 63, wave = tid >> 6;
  const int r16 = lane & 15, h4 = lane >> 4;
  const int q0 = qb * 64;
  const int qw = q0 + wave * 16;

  // Q fragments (already RMS-normed, RoPE'd, pre-scaled by 1/sqrt(128))
  short8 qf[4];
  {
    const u16* qrow = qkv + (size_t)(b * S + qw + r16) * NQKV + h * 128 + h4 * 8;
#pragma unroll
    for (int s4 = 0; s4 < 4; ++s4)
      qf[s4] = *reinterpret_cast<const short8*>(qrow + s4 * 32);
  }

  float mrow[4], lrow[4];
  f32x4 o[8] = {};
#pragma unroll
  for (int r = 0; r < 4; ++r) { mrow[r] = -INFINITY; lrow[r] = 0.f; }

  const int ntiles = qb + 1;
  for (int kt = 0; kt < ntiles; ++kt) {
    const int k0 = kt * 64;
    __syncthreads();
    // stage K tile [64 keys][128 d] and V tile [128 d][64 keys]
    {
      const u16* kbase = qkv + 4096 + (size_t)kvh * 128;
#pragma unroll
      for (int it = 0; it < 4; ++it) {
        int c = tid + it * 256;               // 1024 chunks of 8 elems
        int key = c >> 4, col = (c & 15) * 8;
        int4 val = *reinterpret_cast<const int4*>(kbase + (size_t)(b * S + k0 + key) * NQKV + col);
        int dstIdx = (key * 128 + col) ^ ((key & 7) << 3);
        *reinterpret_cast<int4*>(&Klds[dstIdx]) = val;
      }
      const u16* vbase = vt + (size_t)(b * 8 + kvh) * 128 * S;
#pragma unroll
      for (int it = 0; it < 4; ++it) {
        int c = tid + it * 256;
        int d = c >> 3, col = (c & 7) * 8;
        int4 val = *reinterpret_cast<const int4*>(vbase + (size_t)d * S + k0 + col);
        int dstIdx = (d * 64 + col) ^ ((d & 7) << 3);
        *reinterpret_cast<int4*>(&Vlds[dstIdx]) = val;
      }
    }
    __syncthreads();

    // S = Q K^T (scaled already)
    f32x4 sacc[4] = {};
#pragma unroll
    for (int f = 0; f < 4; ++f) {
#pragma unroll
      for (int s4 = 0; s4 < 4; ++s4) {
        int key = f * 16 + r16;
        int idx = (key * 128 + s4 * 32 + h4 * 8) ^ ((key & 7) << 3);
        short8 kf = *reinterpret_cast<const short8*>(&Klds[idx]);
        sacc[f] = __builtin_amdgcn_mfma_f32_16x16x32_bf16(qf[s4], kf, sacc[f], 0, 0, 0);
      }
    }
    // causal mask (only the diagonal tile needs it)
    if (kt == qb) {
#pragma unroll
      for (int f = 0; f < 4; ++f)
#pragma unroll
        for (int r = 0; r < 4; ++r) {
          int key = k0 + f * 16 + r16;
          int row = qw + h4 * 4 + r;
          if (key > row) sacc[f][r] = -1e30f;
        }
    }
    // online softmax update (rows live in 16-lane groups)
    float fac[4];
#pragma unroll
    for (int r = 0; r < 4; ++r) {
      float mx = fmaxf(fmaxf(sacc[0][r], sacc[1][r]), fmaxf(sacc[2][r], sacc[3][r]));
#pragma unroll
      for (int m = 1; m < 16; m <<= 1) mx = fmaxf(mx, __shfl_xor(mx, m, 64));
      float mn = fmaxf(mrow[r], mx);
      fac[r] = __expf(mrow[r] - mn);
      mrow[r] = mn;
      float psum = 0.f;
#pragma unroll
      for (int f = 0; f < 4; ++f) {
        float p = __expf(sacc[f][r] - mn);
        sacc[f][r] = p;
        psum += p;
      }
#pragma unroll
      for (int m = 1; m < 16; m <<= 1) psum += __shfl_xor(psum, m, 64);
      lrow[r] = lrow[r] * fac[r] + psum;
    }
#pragma unroll
    for (int df = 0; df < 8; ++df)
#pragma unroll
      for (int r = 0; r < 4; ++r) o[df][r] *= fac[r];
    // P -> LDS (bf16)
#pragma unroll
    for (int f = 0; f < 4; ++f)
#pragma unroll
      for (int r = 0; r < 4; ++r) {
        int row = h4 * 4 + r;
        int idx = (row * 64 + f * 16 + r16) ^ ((row & 7) << 3);
        Plds[wave][idx] = f2b(sacc[f][r]);
      }
    __syncthreads();
    // O += P V
    short8 pf[2];
#pragma unroll
    for (int ks = 0; ks < 2; ++ks) {
      int idx = (r16 * 64 + ks * 32 + h4 * 8) ^ ((r16 & 7) << 3);
      pf[ks] = *reinterpret_cast<const short8*>(&Plds[wave][idx]);
    }
#pragma unroll
    for (int df = 0; df < 8; ++df) {
#pragma unroll
      for (int ks = 0; ks < 2; ++ks) {
        int d = df * 16 + r16;
        int idx = (d * 64 + ks * 32 + h4 * 8) ^ ((d & 7) << 3);
        short8 vf = *reinterpret_cast<const short8*>(&Vlds[idx]);
        o[df] = __builtin_amdgcn_mfma_f32_16x16x32_bf16(pf[ks], vf, o[df], 0, 0, 0);
      }
    }
  }

  // epilogue: normalize and store bf16 [token][h*128+d]
#pragma unroll
  for (int df = 0; df < 8; ++df)
#pragma unroll
    for (int r = 0; r < 4; ++r) {
      int row = qw + h4 * 4 + r;
      float val = o[df][r] / lrow[r];
      out[(size_t)(b * S + row) * 4096 + h * 128 + df * 16 + r16] = f2b(val);
    }
}

// ---------------------------------------------------------------------------------------
extern "C" void kernel_launch(void* const* d_in, const int* in_sizes, int n_in,
                              void* d_out, int out_size, void* d_ws, size_t ws_size,
                              hipStream_t stream) {
  const float* hs  = (const float*)d_in[0];
  const int*   pos = (const int*)d_in[1];
  const float* Wq  = (const float*)d_in[2];
  const float* Wk  = (const float*)d_in[3];
  const float* Wv  = (const float*)d_in[4];
  const float* Wo  = (const float*)d_in[5];
  const float* qnw = (const float*)d_in[6];
  const float* knw = (const float*)d_in[7];

  char* ws = (char*)d_ws;
  // layout (bytes):
  //   X / ATTN : 0                 .. 64MB   (X dead after gemm1; attn reuses)
  //   WT / WOT : 67108864          .. +48MB  (WqkvT dead after gemm1; WoT reuses)
  //   QKV      : 117440512         .. +96MB
  //   VT       : 218103808         .. +16MB
  //   TAB      : 234881024         .. +4MB
  u16*   X    = (u16*)(ws);
  u16*   WT   = (u16*)(ws + 67108864);
  u16*   QKV  = (u16*)(ws + 117440512);
  u16*   VT   = (u16*)(ws + 218103808);
  float2* TAB = (float2*)(ws + 234881024);
  u16*   ATTN = X;
  u16*   WOT  = WT;

  // 1. hidden f32 -> bf16
  k_cvt_bf16<<<(TOK * DM / 4) / 256, 256, 0, stream>>>(hs, X);
  // 2. weight transposes into fused [6144][4096] operand
  k_tr_w<<<dim3(128, 128), dim3(32, 8), 0, stream>>>(Wq, WT, 4096);
  k_tr_w<<<dim3(32, 128),  dim3(32, 8), 0, stream>>>(Wk, WT + (size_t)4096 * 4096, 1024);
  k_tr_w<<<dim3(32, 128),  dim3(32, 8), 0, stream>>>(Wv, WT + (size_t)5120 * 4096, 1024);
  // 3. RoPE table
  k_rope_tab<<<TOK, 64, 0, stream>>>(pos, TAB);
  // 4. QKV GEMM: [8192,4096] x [6144,4096]^T -> bf16 qkv
  k_gemm_bt<1><<<(8192 / 128) * (6144 / 128), 256, 0, stream>>>(X, WT, QKV, 8192, 6144, 4096);
  // 5. RMSNorm + RoPE in place (q scaled by 1/sqrt(128))
  k_norm_rope<<<TOK * 40 / 4, 256, 0, stream>>>(QKV, TAB, qnw, knw);
  // 6. V transpose to [b][kvh][d][s]
  k_tr_v<<<dim3(4, 16, 128), dim3(32, 8), 0, stream>>>(QKV, VT);
  // 7. Wo transpose (reuses WT region -- safe: after gemm1 in stream order)
  k_tr_w<<<dim3(128, 128), dim3(32, 8), 0, stream>>>(Wo, WOT, 4096);
  // 8. attention -> ATTN (reuses X region -- safe: after gemm1)
  k_attn<<<dim3(8, 32, 16), 256, 0, stream>>>(QKV, VT, ATTN);
  // 9. output projection -> d_out (f32)
  k_gemm_bt<0><<<(8192 / 128) * (4096 / 128), 256, 0, stream>>>(ATTN, WOT, d_out, 8192, 4096, 4096);
}

// Round 2
// 1210.534 us; speedup vs baseline: 1.2915x; 1.2915x over previous
//
#include <hip/hip_runtime.h>

typedef unsigned short u16;
typedef __attribute__((ext_vector_type(4))) unsigned short u16x4;
typedef __attribute__((ext_vector_type(8))) short short8;
typedef __attribute__((ext_vector_type(4))) float f32x4;

#define DEV static __device__ __forceinline__

constexpr int NB   = 16;
constexpr int S    = 512;
constexpr int DM   = 4096;
constexpr int NH   = 32;
constexpr int NKV  = 8;
constexpr int HD   = 128;
constexpr int TOK  = NB * S;          // 8192
constexpr int NQKV = 6144;            // 4096 q + 1024 k + 1024 v
constexpr float ATT_SCALE = 0.08838834764831845f;  // 1/sqrt(128)

DEV u16 f2b(float f) {
  union { float f; unsigned u; } v; v.f = f;
  unsigned r = v.u + 0x7fffu + ((v.u >> 16) & 1u);
  return (u16)(r >> 16);
}
DEV float b2f(u16 u) {
  union { unsigned u; float f; } v; v.u = ((unsigned)u) << 16;
  return v.f;
}
DEV void async16(const void* g, void* l) {
  __builtin_amdgcn_global_load_lds(
      (const __attribute__((address_space(1))) unsigned int*)g,
      (__attribute__((address_space(3))) unsigned int*)l, 16, 0, 0);
}

// ---------------- f32 -> bf16 convert (hidden states) ----------------
__global__ void k_cvt_bf16(const float* __restrict__ src, u16* __restrict__ dst) {
  int i = (blockIdx.x * 256 + threadIdx.x) * 4;
  const float4 v = *reinterpret_cast<const float4*>(src + i);
  u16x4 o;
  o[0] = f2b(v.x); o[1] = f2b(v.y); o[2] = f2b(v.z); o[3] = f2b(v.w);
  *reinterpret_cast<u16x4*>(dst + i) = o;
}

// ---------------- weight transpose: src[K=4096][ncols] f32 -> dst[ncols][4096] bf16 ----
__global__ void k_tr_w(const float* __restrict__ src, u16* __restrict__ dst, int ncols) {
  __shared__ float tile[32][33];
  int tx = threadIdx.x, ty = threadIdx.y;
  int n0 = blockIdx.x * 32, k0 = blockIdx.y * 32;
#pragma unroll
  for (int i = 0; i < 32; i += 8)
    tile[ty + i][tx] = src[(size_t)(k0 + ty + i) * ncols + n0 + tx];
  __syncthreads();
#pragma unroll
  for (int i = 0; i < 32; i += 8)
    dst[(size_t)(n0 + ty + i) * 4096 + k0 + tx] = f2b(tile[tx][ty + i]);
}

// ---------------- RoPE cos/sin table per (b,s) ----------------
__global__ void k_rope_tab(const int* __restrict__ pos_ids, float2* __restrict__ tab) {
  int t = blockIdx.x;      // 0..8191
  int j = threadIdx.x;     // 0..63
  float pos = (float)pos_ids[t];
  float inv = expf(-(float)j * 0.21586735246819178f);
  float ang = pos * inv;
  float sv, cv;
  sincosf(ang, &sv, &cv);
  tab[t * 64 + j] = make_float2(cv, sv);
}

// ---------------- fused RMSNorm + RoPE, in-place on qkv (q and k heads) ----------------
__global__ void k_norm_rope(u16* __restrict__ qkv, const float2* __restrict__ tab,
                            const float* __restrict__ qw, const float* __restrict__ kw) {
  int wid  = blockIdx.x * 4 + (threadIdx.x >> 6);
  int lane = threadIdx.x & 63;
  int t  = wid / 40;
  int hh = wid - t * 40;
  bool isq = hh < 32;
  u16* base = qkv + (size_t)t * NQKV + (isq ? hh * 128 : 4096 + (hh - 32) * 128);
  float x1 = b2f(base[lane]);
  float x2 = b2f(base[lane + 64]);
  float ss = x1 * x1 + x2 * x2;
#pragma unroll
  for (int m = 1; m < 64; m <<= 1) ss += __shfl_xor(ss, m, 64);
  float r = rsqrtf(ss * (1.0f / 128.0f) + 1e-6f);
  const float* w = isq ? qw : kw;
  float y1 = x1 * r * w[lane];
  float y2 = x2 * r * w[lane + 64];
  float2 cs = tab[t * 64 + lane];
  float o1 = y1 * cs.x - y2 * cs.y;
  float o2 = y2 * cs.x + y1 * cs.y;
  if (isq) { o1 *= ATT_SCALE; o2 *= ATT_SCALE; }
  base[lane]      = f2b(o1);
  base[lane + 64] = f2b(o2);
}

// ---------------- V transpose: qkv v-cols [b][s][kvh][d] -> vt[b][kvh][d][s] ----------
__global__ void k_tr_v(const u16* __restrict__ qkv, u16* __restrict__ vt) {
  __shared__ u16 tile[32][33];
  int bh = blockIdx.z;           // b*8+kvh
  int b = bh >> 3, kvh = bh & 7;
  int d0 = blockIdx.x * 32, s0 = blockIdx.y * 32;
  int tx = threadIdx.x, ty = threadIdx.y;
#pragma unroll
  for (int i = 0; i < 32; i += 8)
    tile[ty + i][tx] = qkv[(size_t)(b * S + s0 + ty + i) * NQKV + 5120 + kvh * 128 + d0 + tx];
  __syncthreads();
#pragma unroll
  for (int i = 0; i < 32; i += 8)
    vt[((size_t)(bh * 128 + d0 + ty + i)) * S + s0 + tx] = tile[tx][ty + i];
}

// =======================================================================================
// 256x256 8-phase GEMM (T2+T3+T4+T5): C[M][N] = A[M][K] * B[N][K]^T, bf16 in, f32 acc.
// 512 threads = 8 waves (2M x 4N). BK=64, double-buffered 128KiB LDS.
// LDS swizzle: 16B chunk kc stored at kc^(row&7); implemented as linear global_load_lds
// dest + inverse-swizzled global source (rule 21); reads apply the same XOR.
// Stage rotation per phase: [B0(t+1)] [A0(t+2)] [B1(t+2)] [A1(t+2)] | [B0(t+2)] ...
// each stage lands exactly one phase after the current tile's last read of that region.
// vmcnt(6) only at phases 4 and 8. Raw s_barrier (no vmcnt drain).
// Region halves (per 256-row op tile): A-half h = rows with bit6==h (waves are 2x128 in M),
//                                      B-half h = rows with bit5==h (waves are 4x64 in N).
// =======================================================================================
template <int OUT_BF16>
__global__ __launch_bounds__(512, 2) void k_gemm8(const u16* __restrict__ A,
                                                  const u16* __restrict__ Bm,
                                                  void* __restrict__ Cv,
                                                  int M, int N, int K) {
  __shared__ alignas(16) u16 lds[2][2][256 * 64];   // [buf][A/B][row*64+col]
  const int tid  = threadIdx.x;
  const int lane = tid & 63;
  const int wave = tid >> 6;
  const int r16 = lane & 15, h4 = lane >> 4;
  const int wm = (wave >> 2) * 128, wn = (wave & 3) * 64;

  // block mapping: bijective XCD chunking + group-M(8) 2D tiling for L2/L3 locality
  const int nbx = N >> 8;
  const int nby = M >> 8;
  const int nwg = nby * nbx;
  const int cpx = nwg >> 3;
  const int wg  = blockIdx.x;
  const int gidx = (wg & 7) * cpx + (wg >> 3);
  const int GR = 8;                       // by-rows per group (nby % 8 == 0 here)
  const int grp = gidx / (GR * nbx);
  const int rem = gidx - grp * (GR * nbx);
  const int by = grp * GR + (rem % GR);
  const int bx = rem / GR;
  const int m0 = by << 8, n0 = bx << 8;

  const int NKT = K >> 6;
  const int NIT = NKT >> 1;

  f32x4 acc[8][4] = {};
  short8 af[4][2];
  short8 bfr[2][2];

  // --- staging: one half-tile (128 rows x 64 cols) = 2 global_load_lds per thread ---
  auto stage = [&](int s) {
    int ts = s >> 2; if (ts > NKT - 1) ts = NKT - 1;
    const int sel  = s & 3;               // 0:A-h0  1:B-h1  2:A-h1  3:B-h0
    const int isB  = sel & 1;
    const int half = (sel == 1 || sel == 2) ? 1 : 0;
    const u16* G = isB ? Bm : A;
    const int base0 = isB ? n0 : m0;
    u16* lb = &lds[ts & 1][isB][0];
    const int k0 = ts << 6;
#pragma unroll
    for (int j = 0; j < 2; ++j) {
      int c = (j << 9) + tid;             // 0..1023 chunks
      int rl = c >> 3, kcd = c & 7;
      int row = isB ? ((rl & 31) | (half << 5) | ((rl >> 5) << 6))
                    : ((rl & 63) | (half << 6) | ((rl >> 6) << 7));
      int kc = kcd ^ (row & 7);           // inverse-swizzled source column chunk
      async16(G + (size_t)(base0 + row) * K + k0 + (kc << 3),
              lb + row * 64 + (kcd << 3));
    }
  };
  auto ldA = [&](int buf, int mf, int ks) {
    int row = wm + mf * 16 + r16;
    int kc = ((ks << 2) + h4) ^ (r16 & 7);
    return *reinterpret_cast<const short8*>(&lds[buf][0][row * 64 + (kc << 3)]);
  };
  auto ldB = [&](int buf, int nf, int ks) {
    int row = wn + nf * 16 + r16;
    int kc = ((ks << 2) + h4) ^ (r16 & 7);
    return *reinterpret_cast<const short8*>(&lds[buf][1][row * 64 + (kc << 3)]);
  };

  // --- prologue: tile0 (4 halves) + 3 halves of tile1 in flight ---
#pragma unroll
  for (int s = 0; s < 7; ++s) stage(s);
  asm volatile("s_waitcnt vmcnt(6)" ::: "memory");
  __builtin_amdgcn_s_barrier();

  for (int i = 0; i < NIT; ++i) {
#pragma unroll
    for (int ph = 0; ph < 2; ++ph) {      // ph=0: tile 2i (buf0); ph=1: tile 2i+1 (buf1)
      const int buf = ph;
#pragma unroll
      for (int g = 0; g < 4; ++g) {
        // (a) ds-read register subtile
        if (g == 0) {
#pragma unroll
          for (int mf = 0; mf < 4; ++mf)
#pragma unroll
            for (int ks = 0; ks < 2; ++ks) af[mf][ks] = ldA(buf, mf, ks);
#pragma unroll
          for (int nf = 0; nf < 2; ++nf)
#pragma unroll
            for (int ks = 0; ks < 2; ++ks) bfr[nf][ks] = ldB(buf, nf, ks);
        } else if (g == 1) {
#pragma unroll
          for (int nf = 0; nf < 2; ++nf)
#pragma unroll
            for (int ks = 0; ks < 2; ++ks) bfr[nf][ks] = ldB(buf, 2 + nf, ks);
        } else if (g == 2) {
#pragma unroll
          for (int mf = 0; mf < 4; ++mf)
#pragma unroll
            for (int ks = 0; ks < 2; ++ks) af[mf][ks] = ldA(buf, 4 + mf, ks);
        } else {
#pragma unroll
          for (int nf = 0; nf < 2; ++nf)
#pragma unroll
            for (int ks = 0; ks < 2; ++ks) bfr[nf][ks] = ldB(buf, nf, ks);
        }
        // (b) stage one half-tile prefetch
        stage(7 + i * 8 + ph * 4 + g);
        if (g == 0) asm volatile("s_waitcnt lgkmcnt(8)" ::: "memory");
        // (c) mid barrier, (d) LDS drain for this wave's reads
        __builtin_amdgcn_s_barrier();
        asm volatile("s_waitcnt lgkmcnt(0)" ::: "memory");
        __builtin_amdgcn_sched_barrier(0);
        // (e) MFMA cluster: one C-quadrant x K=64
        __builtin_amdgcn_s_setprio(1);
        const int mo = (g >= 2) ? 4 : 0;
        const int no = (g == 1 || g == 2) ? 2 : 0;
#pragma unroll
        for (int mf = 0; mf < 4; ++mf)
#pragma unroll
          for (int nf = 0; nf < 2; ++nf)
#pragma unroll
            for (int ks = 0; ks < 2; ++ks)
              acc[mo + mf][no + nf] = __builtin_amdgcn_mfma_f32_16x16x32_bf16(
                  af[mf][ks], bfr[nf][ks], acc[mo + mf][no + nf], 0, 0, 0);
        __builtin_amdgcn_s_setprio(0);
        // (f) counted vmcnt once per K-tile: next tile's 4 halves have landed
        if (g == 3) asm volatile("s_waitcnt vmcnt(6)" ::: "memory");
        __builtin_amdgcn_s_barrier();
      }
    }
  }

  // epilogue: C/D layout col=lane&15, row=(lane>>4)*4+reg
  if (OUT_BF16) {
    u16* C = (u16*)Cv;
#pragma unroll
    for (int mf = 0; mf < 8; ++mf)
#pragma unroll
      for (int nf = 0; nf < 4; ++nf)
#pragma unroll
        for (int r = 0; r < 4; ++r) {
          size_t row = m0 + wm + mf * 16 + h4 * 4 + r;
          size_t col = n0 + wn + nf * 16 + r16;
          C[row * N + col] = f2b(acc[mf][nf][r]);
        }
  } else {
    float* C = (float*)Cv;
#pragma unroll
    for (int mf = 0; mf < 8; ++mf)
#pragma unroll
      for (int nf = 0; nf < 4; ++nf)
#pragma unroll
        for (int r = 0; r < 4; ++r) {
          size_t row = m0 + wm + mf * 16 + h4 * 4 + r;
          size_t col = n0 + wn + nf * 16 + r16;
          C[row * N + col] = acc[mf][nf][r];
        }
  }
}

// ---------------- flash attention (causal, GQA) ----------------------------------------
__global__ __launch_bounds__(256) void k_attn(const u16* __restrict__ qkv,
                                              const u16* __restrict__ vt,
                                              u16* __restrict__ out) {
  __shared__ u16 Klds[64 * 128];     // [key][d], XOR-swizzled
  __shared__ u16 Vlds[128 * 64];     // [d][key], XOR-swizzled
  __shared__ u16 Plds[4][16 * 64];   // per-wave P, XOR-swizzled
  const int qb = blockIdx.x, h = blockIdx.y, b = blockIdx.z;
  const int kvh = h >> 2;
  const int tid = threadIdx.x, lane = tid & 63, wave = tid >> 6;
  const int r16 = lane & 15, h4 = lane >> 4;
  const int q0 = qb * 64;
  const int qw = q0 + wave * 16;

  short8 qf[4];
  {
    const u16* qrow = qkv + (size_t)(b * S + qw + r16) * NQKV + h * 128 + h4 * 8;
#pragma unroll
    for (int s4 = 0; s4 < 4; ++s4)
      qf[s4] = *reinterpret_cast<const short8*>(qrow + s4 * 32);
  }

  float mrow[4], lrow[4];
  f32x4 o[8] = {};
#pragma unroll
  for (int r = 0; r < 4; ++r) { mrow[r] = -INFINITY; lrow[r] = 0.f; }

  const int ntiles = qb + 1;
  for (int kt = 0; kt < ntiles; ++kt) {
    const int k0 = kt * 64;
    __syncthreads();
    {
      const u16* kbase = qkv + 4096 + (size_t)kvh * 128;
#pragma unroll
      for (int it = 0; it < 4; ++it) {
        int c = tid + it * 256;
        int key = c >> 4, col = (c & 15) * 8;
        int4 val = *reinterpret_cast<const int4*>(kbase + (size_t)(b * S + k0 + key) * NQKV + col);
        int dstIdx = (key * 128 + col) ^ ((key & 7) << 3);
        *reinterpret_cast<int4*>(&Klds[dstIdx]) = val;
      }
      const u16* vbase = vt + (size_t)(b * 8 + kvh) * 128 * S;
#pragma unroll
      for (int it = 0; it < 4; ++it) {
        int c = tid + it * 256;
        int d = c >> 3, col = (c & 7) * 8;
        int4 val = *reinterpret_cast<const int4*>(vbase + (size_t)d * S + k0 + col);
        int dstIdx = (d * 64 + col) ^ ((d & 7) << 3);
        *reinterpret_cast<int4*>(&Vlds[dstIdx]) = val;
      }
    }
    __syncthreads();

    f32x4 sacc[4] = {};
#pragma unroll
    for (int f = 0; f < 4; ++f) {
#pragma unroll
      for (int s4 = 0; s4 < 4; ++s4) {
        int key = f * 16 + r16;
        int idx = (key * 128 + s4 * 32 + h4 * 8) ^ ((key & 7) << 3);
        short8 kf = *reinterpret_cast<const short8*>(&Klds[idx]);
        sacc[f] = __builtin_amdgcn_mfma_f32_16x16x32_bf16(qf[s4], kf, sacc[f], 0, 0, 0);
      }
    }
    if (kt == qb) {
#pragma unroll
      for (int f = 0; f < 4; ++f)
#pragma unroll
        for (int r = 0; r < 4; ++r) {
          int key = k0 + f * 16 + r16;
          int row = qw + h4 * 4 + r;
          if (key > row) sacc[f][r] = -1e30f;
        }
    }
    float fac[4];
#pragma unroll
    for (int r = 0; r < 4; ++r) {
      float mx = fmaxf(fmaxf(sacc[0][r], sacc[1][r]), fmaxf(sacc[2][r], sacc[3][r]));
#pragma unroll
      for (int m = 1; m < 16; m <<= 1) mx = fmaxf(mx, __shfl_xor(mx, m, 64));
      float mn = fmaxf(mrow[r], mx);
      fac[r] = __expf(mrow[r] - mn);
      mrow[r] = mn;
      float psum = 0.f;
#pragma unroll
      for (int f = 0; f < 4; ++f) {
        float p = __expf(sacc[f][r] - mn);
        sacc[f][r] = p;
        psum += p;
      }
#pragma unroll
      for (int m = 1; m < 16; m <<= 1) psum += __shfl_xor(psum, m, 64);
      lrow[r] = lrow[r] * fac[r] + psum;
    }
#pragma unroll
    for (int df = 0; df < 8; ++df)
#pragma unroll
      for (int r = 0; r < 4; ++r) o[df][r] *= fac[r];
#pragma unroll
    for (int f = 0; f < 4; ++f)
#pragma unroll
      for (int r = 0; r < 4; ++r) {
        int row = h4 * 4 + r;
        int idx = (row * 64 + f * 16 + r16) ^ ((row & 7) << 3);
        Plds[wave][idx] = f2b(sacc[f][r]);
      }
    __syncthreads();
    short8 pf[2];
#pragma unroll
    for (int ks = 0; ks < 2; ++ks) {
      int idx = (r16 * 64 + ks * 32 + h4 * 8) ^ ((r16 & 7) << 3);
      pf[ks] = *reinterpret_cast<const short8*>(&Plds[wave][idx]);
    }
#pragma unroll
    for (int df = 0; df < 8; ++df) {
#pragma unroll
      for (int ks = 0; ks < 2; ++ks) {
        int d = df * 16 + r16;
        int idx = (d * 64 + ks * 32 + h4 * 8) ^ ((d & 7) << 3);
        short8 vf = *reinterpret_cast<const short8*>(&Vlds[idx]);
        o[df] = __builtin_amdgcn_mfma_f32_16x16x32_bf16(pf[ks], vf, o[df], 0, 0, 0);
      }
    }
  }

#pragma unroll
  for (int df = 0; df < 8; ++df)
#pragma unroll
    for (int r = 0; r < 4; ++r) {
      int row = qw + h4 * 4 + r;
      float val = o[df][r] / lrow[r];
      out[(size_t)(b * S + row) * 4096 + h * 128 + df * 16 + r16] = f2b(val);
    }
}

// ---------------------------------------------------------------------------------------
extern "C" void kernel_launch(void* const* d_in, const int* in_sizes, int n_in,
                              void* d_out, int out_size, void* d_ws, size_t ws_size,
                              hipStream_t stream) {
  const float* hs  = (const float*)d_in[0];
  const int*   pos = (const int*)d_in[1];
  const float* Wq  = (const float*)d_in[2];
  const float* Wk  = (const float*)d_in[3];
  const float* Wv  = (const float*)d_in[4];
  const float* Wo  = (const float*)d_in[5];
  const float* qnw = (const float*)d_in[6];
  const float* knw = (const float*)d_in[7];

  char* ws = (char*)d_ws;
  u16*   X    = (u16*)(ws);
  u16*   WT   = (u16*)(ws + 67108864);
  u16*   QKV  = (u16*)(ws + 117440512);
  u16*   VT   = (u16*)(ws + 218103808);
  float2* TAB = (float2*)(ws + 234881024);
  u16*   ATTN = X;
  u16*   WOT  = WT;

  // 1. hidden f32 -> bf16
  k_cvt_bf16<<<(TOK * DM / 4) / 256, 256, 0, stream>>>(hs, X);
  // 2. weight transposes into fused [6144][4096] operand
  k_tr_w<<<dim3(128, 128), dim3(32, 8), 0, stream>>>(Wq, WT, 4096);
  k_tr_w<<<dim3(32, 128),  dim3(32, 8), 0, stream>>>(Wk, WT + (size_t)4096 * 4096, 1024);
  k_tr_w<<<dim3(32, 128),  dim3(32, 8), 0, stream>>>(Wv, WT + (size_t)5120 * 4096, 1024);
  // 3. RoPE table
  k_rope_tab<<<TOK, 64, 0, stream>>>(pos, TAB);
  // 4. QKV GEMM (8-phase 256^2): [8192,4096] x [6144,4096]^T -> bf16 qkv
  k_gemm8<1><<<(8192 / 256) * (6144 / 256), 512, 0, stream>>>(X, WT, QKV, 8192, 6144, 4096);
  // 5. RMSNorm + RoPE in place (q scaled by 1/sqrt(128))
  k_norm_rope<<<TOK * 40 / 4, 256, 0, stream>>>(QKV, TAB, qnw, knw);
  // 6. V transpose to [b][kvh][d][s]
  k_tr_v<<<dim3(4, 16, 128), dim3(32, 8), 0, stream>>>(QKV, VT);
  // 7. Wo transpose (reuses WT region -- safe: after gemm1 in stream order)
  k_tr_w<<<dim3(128, 128), dim3(32, 8), 0, stream>>>(Wo, WOT, 4096);
  // 8. attention -> ATTN (reuses X region -- safe: after gemm1)
  k_attn<<<dim3(8, 32, 16), 256, 0, stream>>>(QKV, VT, ATTN);
  // 9. output projection (8-phase 256^2) -> d_out (f32)
  k_gemm8<0><<<(8192 / 256) * (4096 / 256), 512, 0, stream>>>(ATTN, WOT, d_out, 8192, 4096, 4096);
}